// Round 1
// 8173.649 us; speedup vs baseline: 1.4813x; 1.4813x over previous
//
#include <hip/hip_runtime.h>

#define HID 96

typedef _Float16 h2 __attribute__((ext_vector_type(2)));

__device__ __forceinline__ h2 mkh2(float a, float b) {
    h2 r; r.x = (_Float16)a; r.y = (_Float16)b; return r;
}
__device__ __forceinline__ h2 bc(unsigned u) {
    union { unsigned u; h2 h; } c; c.u = u; return c.h;
}

// 4 packed-dot2 steps: one uint4 (8 halves of h) against weight pairs A..D.
#define DOT4(Q, WA, WB, WC, WD) do {                                  \
    acc0 = __builtin_amdgcn_fdot2(W##WA, bc(Q.x), acc0, false);       \
    acc1 = __builtin_amdgcn_fdot2(W##WB, bc(Q.y), acc1, false);       \
    acc2 = __builtin_amdgcn_fdot2(W##WC, bc(Q.z), acc2, false);       \
    acc3 = __builtin_amdgcn_fdot2(W##WD, bc(Q.w), acc3, false);       \
} while (0)

// Barrier that drains ONLY LDS ops (lgkmcnt), leaving global prefetches
// (vmcnt) in flight — __syncthreads would drain vmcnt(0) every step.
#define BARRIER() asm volatile("s_waitcnt lgkmcnt(0)\n\ts_barrier" ::: "memory")

// 96-wide f32 dot of one LDS history row against w_dense (uniform -> s_loads).
__device__ __forceinline__ float head_dot(const float* hrow, const float* wdp) {
    const float4* hr = reinterpret_cast<const float4*>(hrow);
    const float4* wv = reinterpret_cast<const float4*>(wdp);
    float a0 = 0.f, a1 = 0.f, a2 = 0.f, a3 = 0.f;
    #pragma unroll
    for (int k = 0; k < 24; k += 4) {
        float4 ha = hr[k], hb = hr[k + 1], hc = hr[k + 2], hd = hr[k + 3];
        float4 wa = wv[k], wb = wv[k + 1], wc = wv[k + 2], wd = wv[k + 3];
        a0 = fmaf(ha.w, wa.w, fmaf(ha.z, wa.z, fmaf(ha.y, wa.y, fmaf(ha.x, wa.x, a0))));
        a1 = fmaf(hb.w, wb.w, fmaf(hb.z, wb.z, fmaf(hb.y, wb.y, fmaf(hb.x, wb.x, a1))));
        a2 = fmaf(hc.w, wc.w, fmaf(hc.z, wc.z, fmaf(hc.y, wc.y, fmaf(hc.x, wc.x, a2))));
        a3 = fmaf(hd.w, wd.w, fmaf(hd.z, wd.z, fmaf(hd.y, wd.y, fmaf(hd.x, wd.x, a3))));
    }
    return (a0 + a1) + (a2 + a3);
}

__global__ __launch_bounds__(448)
void lstm_fused(
    const float* __restrict__ x,        // [B,T]
    const float* __restrict__ w_ih,     // [384]
    const float* __restrict__ w_hh,     // [384,96]
    const float* __restrict__ b_ih,     // [384]
    const float* __restrict__ b_hh,     // [384]
    const float* __restrict__ w_dense,  // [96]
    const float* __restrict__ b_dense,  // [1]
    float* __restrict__ out,            // [B,T]
    int T)
{
    const int tid  = threadIdx.x;    // 0..447
    const int lane = tid & 63;
    const int wv   = tid >> 6;       // 0..6: waves 0-5 gates, wave 6 head

    // Double-buffered h (f16, broadcast-read by all gate lanes).
    __shared__ __align__(16) _Float16 hbuf[2][96];
    // 64-step h history (f32) for the dense head; rows padded to 100 dwords
    // (16B-aligned for float4, bank stride 4 -> 8-way worst, off critical path).
    __shared__ __align__(16) float hist[2][64][100];

    if (tid < 96) { hbuf[0][tid] = (_Float16)0.f; hbuf[1][tid] = (_Float16)0.f; }

    const float* xrow = x + (size_t)blockIdx.x * T;
    float*       orow = out + (size_t)blockIdx.x * T;

    __syncthreads();

    if (wv < 6) {
        // ---- gate waves: lane = (unit u, gate g), full 96-dot per lane ----
        const int u = (wv << 4) | (lane & 15);   // hidden unit 0..95
        const int g = lane >> 4;                 // 0=i 1=f 2=g 3=o
        const int j = g * 96 + u;                // w_hh row

        const float4* wr = reinterpret_cast<const float4*>(w_hh + (size_t)j * HID);
        float4 f0 = wr[0], f1 = wr[1], f2  = wr[2],  f3  = wr[3],  f4  = wr[4],  f5  = wr[5];
        float4 f6 = wr[6], f7 = wr[7], f8  = wr[8],  f9  = wr[9],  f10 = wr[10], f11 = wr[11];
        h2 W0  = mkh2(f0.x,  f0.y),  W1  = mkh2(f0.z,  f0.w);
        h2 W2  = mkh2(f1.x,  f1.y),  W3  = mkh2(f1.z,  f1.w);
        h2 W4  = mkh2(f2.x,  f2.y),  W5  = mkh2(f2.z,  f2.w);
        h2 W6  = mkh2(f3.x,  f3.y),  W7  = mkh2(f3.z,  f3.w);
        h2 W8  = mkh2(f4.x,  f4.y),  W9  = mkh2(f4.z,  f4.w);
        h2 W10 = mkh2(f5.x,  f5.y),  W11 = mkh2(f5.z,  f5.w);
        h2 W12 = mkh2(f6.x,  f6.y),  W13 = mkh2(f6.z,  f6.w);
        h2 W14 = mkh2(f7.x,  f7.y),  W15 = mkh2(f7.z,  f7.w);
        h2 W16 = mkh2(f8.x,  f8.y),  W17 = mkh2(f8.z,  f8.w);
        h2 W18 = mkh2(f9.x,  f9.y),  W19 = mkh2(f9.z,  f9.w);
        h2 W20 = mkh2(f10.x, f10.y), W21 = mkh2(f10.z, f10.w);
        h2 W22 = mkh2(f11.x, f11.y), W23 = mkh2(f11.z, f11.w);
        const float4* wr2 = wr + 12;  // same row, elements 48..95
        float4 e0 = wr2[0], e1 = wr2[1], e2  = wr2[2],  e3  = wr2[3],  e4  = wr2[4],  e5  = wr2[5];
        float4 e6 = wr2[6], e7 = wr2[7], e8  = wr2[8],  e9  = wr2[9],  e10 = wr2[10], e11 = wr2[11];
        h2 W24 = mkh2(e0.x,  e0.y),  W25 = mkh2(e0.z,  e0.w);
        h2 W26 = mkh2(e1.x,  e1.y),  W27 = mkh2(e1.z,  e1.w);
        h2 W28 = mkh2(e2.x,  e2.y),  W29 = mkh2(e2.z,  e2.w);
        h2 W30 = mkh2(e3.x,  e3.y),  W31 = mkh2(e3.z,  e3.w);
        h2 W32 = mkh2(e4.x,  e4.y),  W33 = mkh2(e4.z,  e4.w);
        h2 W34 = mkh2(e5.x,  e5.y),  W35 = mkh2(e5.z,  e5.w);
        h2 W36 = mkh2(e6.x,  e6.y),  W37 = mkh2(e6.z,  e6.w);
        h2 W38 = mkh2(e7.x,  e7.y),  W39 = mkh2(e7.z,  e7.w);
        h2 W40 = mkh2(e8.x,  e8.y),  W41 = mkh2(e8.z,  e8.w);
        h2 W42 = mkh2(e9.x,  e9.y),  W43 = mkh2(e9.z,  e9.w);
        h2 W44 = mkh2(e10.x, e10.y), W45 = mkh2(e10.z, e10.w);
        h2 W46 = mkh2(e11.x, e11.y), W47 = mkh2(e11.z, e11.w);
        asm("" : "+v"(W0),  "+v"(W1),  "+v"(W2),  "+v"(W3),  "+v"(W4),  "+v"(W5));
        asm("" : "+v"(W6),  "+v"(W7),  "+v"(W8),  "+v"(W9),  "+v"(W10), "+v"(W11));
        asm("" : "+v"(W12), "+v"(W13), "+v"(W14), "+v"(W15), "+v"(W16), "+v"(W17));
        asm("" : "+v"(W18), "+v"(W19), "+v"(W20), "+v"(W21), "+v"(W22), "+v"(W23));
        asm("" : "+v"(W24), "+v"(W25), "+v"(W26), "+v"(W27), "+v"(W28), "+v"(W29));
        asm("" : "+v"(W30), "+v"(W31), "+v"(W32), "+v"(W33), "+v"(W34), "+v"(W35));
        asm("" : "+v"(W36), "+v"(W37), "+v"(W38), "+v"(W39), "+v"(W40), "+v"(W41));
        asm("" : "+v"(W42), "+v"(W43), "+v"(W44), "+v"(W45), "+v"(W46), "+v"(W47));

        const float wihr = w_ih[j];
        const float bias = b_ih[j] + b_hh[j];
        // gate g==2 is tanh = 2*sig(2x)-1; others sigmoid.
        const bool  isg = (g == 2);
        const float s1  = isg ? 2.f : 1.f;
        const float m1  = isg ? 2.f : 1.f;
        const float d1  = isg ? -1.f : 0.f;

        float c  = 0.f;
        float xs = xrow[0];

        #pragma unroll 1
        for (int t = 0; t < T; ++t) {
            float xs_n = (t + 1 < T) ? xrow[t + 1] : 0.f;

            const uint4* hp = reinterpret_cast<const uint4*>(hbuf[(t & 1) ^ 1]);
            float acc0 = 0.f, acc1 = 0.f, acc2 = 0.f, acc3 = 0.f;
            uint4 qA = hp[0], qB = hp[1], qC = hp[2];
            DOT4(qA, 0, 1, 2, 3);     qA = hp[3];
            DOT4(qB, 4, 5, 6, 7);     qB = hp[4];
            DOT4(qC, 8, 9, 10, 11);   qC = hp[5];
            DOT4(qA, 12, 13, 14, 15); qA = hp[6];
            DOT4(qB, 16, 17, 18, 19); qB = hp[7];
            DOT4(qC, 20, 21, 22, 23); qC = hp[8];
            DOT4(qA, 24, 25, 26, 27); qA = hp[9];
            DOT4(qB, 28, 29, 30, 31); qB = hp[10];
            DOT4(qC, 32, 33, 34, 35); qC = hp[11];
            DOT4(qA, 36, 37, 38, 39);
            DOT4(qB, 40, 41, 42, 43);
            DOT4(qC, 44, 45, 46, 47);

            float v    = (acc0 + acc1) + (acc2 + acc3);
            float pre  = v + fmaf(xs, wihr, bias);
            float actv = fmaf(m1, __builtin_amdgcn_rcpf(1.f + __expf(-s1 * pre)), d1);

            // gather f,g,o to the i-lanes (all within this wave)
            float fv = __shfl_xor(actv, 16, 64);
            float gv = __shfl_xor(actv, 32, 64);
            float ov = __shfl_xor(actv, 48, 64);

            if (lane < 16) {      // g==0 lanes own the state of unit u
                c = fmaf(fv, c, actv * gv);
                float th = fmaf(2.f, __builtin_amdgcn_rcpf(1.f + __expf(-2.f * c)), -1.f);
                float h  = ov * th;
                hbuf[t & 1][u] = (_Float16)h;          // matvec path (f16)
                hist[(t >> 6) & 1][t & 63][u] = h;     // head path (f32)
            }
            BARRIER();
            xs = xs_n;
        }
    } else {
        // ---- head wave: one burst of 64 outputs per 64-step window ----
        const float bd = b_dense[0];
        #pragma unroll 1
        for (int t = 0; t < T; ++t) {
            if (t && (t & 63) == 0) {
                const int buf = ((t >> 6) - 1) & 1;    // completed window's buffer
                float a = head_dot(&hist[buf][lane][0], w_dense);
                orow[t - 64 + lane] = a + bd;
            }
            BARRIER();
        }
        // tail: rows [T0, T)
        const int T0 = ((T - 1) >> 6) << 6;
        if (lane < T - T0) {
            const int buf = (T0 >> 6) & 1;
            float a = head_dot(&hist[buf][lane][0], w_dense);
            orow[T0 + lane] = a + bd;
        }
    }
}

extern "C" void kernel_launch(void* const* d_in, const int* in_sizes, int n_in,
                              void* d_out, int out_size, void* d_ws, size_t ws_size,
                              hipStream_t stream) {
    const float* x   = (const float*)d_in[0];
    const float* wih = (const float*)d_in[1];
    const float* whh = (const float*)d_in[2];
    const float* bih = (const float*)d_in[3];
    const float* bhh = (const float*)d_in[4];
    const float* wd  = (const float*)d_in[5];
    const float* bd  = (const float*)d_in[6];
    float* out = (float*)d_out;

    const int B = 32;
    const int T = in_sizes[0] / B;   // x is [B,T,1]

    lstm_fused<<<dim3(B), dim3(448), 0, stream>>>(x, wih, whh, bih, bhh, wd, bd, out, T);
}

// Round 3
// 8139.479 us; speedup vs baseline: 1.4876x; 1.0042x over previous
//
#include <hip/hip_runtime.h>

#define HID 96

typedef _Float16 h2 __attribute__((ext_vector_type(2)));

__device__ __forceinline__ h2 mkh2(float a, float b) {
    h2 r; r.x = (_Float16)a; r.y = (_Float16)b; return r;
}
__device__ __forceinline__ h2 bc(unsigned u) {
    union { unsigned u; h2 h; } c; c.u = u; return c.h;
}

// DPP quad-perm lane exchange (VALU, no LDS): ctrl 0xB1=xor1, 0x4E=xor2, 0x1B=xor3
template <int CTRL>
__device__ __forceinline__ float dpp_q(float v) {
    int i = __builtin_bit_cast(int, v);
    int r = __builtin_amdgcn_update_dpp(0, i, CTRL, 0xF, 0xF, true);
    return __builtin_bit_cast(float, r);
}

// 4 packed-dot2 steps: one uint4 (8 halves of h) against weight pairs A..D.
#define DOT4(Q, WA, WB, WC, WD) do {                                  \
    acc0 = __builtin_amdgcn_fdot2(W##WA, bc(Q.x), acc0, false);       \
    acc1 = __builtin_amdgcn_fdot2(W##WB, bc(Q.y), acc1, false);       \
    acc2 = __builtin_amdgcn_fdot2(W##WC, bc(Q.z), acc2, false);       \
    acc3 = __builtin_amdgcn_fdot2(W##WD, bc(Q.w), acc3, false);       \
} while (0)

// Barrier that drains ONLY LDS ops (lgkmcnt), leaving global prefetches
// (vmcnt) in flight — __syncthreads would drain vmcnt(0) every step.
#define BARRIER() asm volatile("s_waitcnt lgkmcnt(0)\n\ts_barrier" ::: "memory")

// 96-wide f32 dot of one LDS history row against w_dense.
__device__ __forceinline__ float head_dot(const float* hrow, const float* wdp) {
    const float4* hr = reinterpret_cast<const float4*>(hrow);
    const float4* wv = reinterpret_cast<const float4*>(wdp);
    float a0 = 0.f, a1 = 0.f, a2 = 0.f, a3 = 0.f;
    #pragma unroll
    for (int k = 0; k < 24; k += 4) {
        float4 ha = hr[k], hb = hr[k + 1], hc = hr[k + 2], hd = hr[k + 3];
        float4 wa = wv[k], wb = wv[k + 1], wc = wv[k + 2], wd = wv[k + 3];
        a0 = fmaf(ha.w, wa.w, fmaf(ha.z, wa.z, fmaf(ha.y, wa.y, fmaf(ha.x, wa.x, a0))));
        a1 = fmaf(hb.w, wb.w, fmaf(hb.z, wb.z, fmaf(hb.y, wb.y, fmaf(hb.x, wb.x, a1))));
        a2 = fmaf(hc.w, wc.w, fmaf(hc.z, wc.z, fmaf(hc.y, wc.y, fmaf(hc.x, wc.x, a2))));
        a3 = fmaf(hd.w, wd.w, fmaf(hd.z, wd.z, fmaf(hd.y, wd.y, fmaf(hd.x, wd.x, a3))));
    }
    return (a0 + a1) + (a2 + a3);
}

__global__ __launch_bounds__(448)
void lstm_fused(
    const float* __restrict__ x,        // [B,T]
    const float* __restrict__ w_ih,     // [384]
    const float* __restrict__ w_hh,     // [384,96]
    const float* __restrict__ b_ih,     // [384]
    const float* __restrict__ b_hh,     // [384]
    const float* __restrict__ w_dense,  // [96]
    const float* __restrict__ b_dense,  // [1]
    float* __restrict__ out,            // [B,T]
    int T)
{
    const int tid  = threadIdx.x;    // 0..447
    const int lane = tid & 63;
    const int wv   = tid >> 6;       // 0..6: waves 0-5 gates, wave 6 head

    // Double-buffered h (f16, broadcast-read by all gate lanes).
    __shared__ __align__(16) _Float16 hbuf[2][96];
    // 64-step h history (f32) for the dense head; rows stride 100 dwords
    // (16B-aligned; lane-offset 16B mod 128 -> stride-1-equivalent banking).
    __shared__ __align__(16) float hist[2][64][100];

    if (tid < 96) { hbuf[0][tid] = (_Float16)0.f; hbuf[1][tid] = (_Float16)0.f; }

    const float* xrow = x + (size_t)blockIdx.x * T;
    float*       orow = out + (size_t)blockIdx.x * T;

    __syncthreads();

    if (wv < 6) {
        // ---- gate waves: quad layout — lane = ((u&15)<<2) | g ----
        const int g = lane & 3;                  // 0=i 1=f 2=g 3=o
        const int u = (wv << 4) | (lane >> 2);   // hidden unit 0..95
        const int j = g * 96 + u;                // w_hh row

        const float4* wr = reinterpret_cast<const float4*>(w_hh + (size_t)j * HID);
        float4 f0 = wr[0], f1 = wr[1], f2  = wr[2],  f3  = wr[3],  f4  = wr[4],  f5  = wr[5];
        float4 f6 = wr[6], f7 = wr[7], f8  = wr[8],  f9  = wr[9],  f10 = wr[10], f11 = wr[11];
        h2 W0  = mkh2(f0.x,  f0.y),  W1  = mkh2(f0.z,  f0.w);
        h2 W2  = mkh2(f1.x,  f1.y),  W3  = mkh2(f1.z,  f1.w);
        h2 W4  = mkh2(f2.x,  f2.y),  W5  = mkh2(f2.z,  f2.w);
        h2 W6  = mkh2(f3.x,  f3.y),  W7  = mkh2(f3.z,  f3.w);
        h2 W8  = mkh2(f4.x,  f4.y),  W9  = mkh2(f4.z,  f4.w);
        h2 W10 = mkh2(f5.x,  f5.y),  W11 = mkh2(f5.z,  f5.w);
        h2 W12 = mkh2(f6.x,  f6.y),  W13 = mkh2(f6.z,  f6.w);
        h2 W14 = mkh2(f7.x,  f7.y),  W15 = mkh2(f7.z,  f7.w);
        h2 W16 = mkh2(f8.x,  f8.y),  W17 = mkh2(f8.z,  f8.w);
        h2 W18 = mkh2(f9.x,  f9.y),  W19 = mkh2(f9.z,  f9.w);
        h2 W20 = mkh2(f10.x, f10.y), W21 = mkh2(f10.z, f10.w);
        h2 W22 = mkh2(f11.x, f11.y), W23 = mkh2(f11.z, f11.w);
        const float4* wr2 = wr + 12;  // same row, elements 48..95
        float4 e0 = wr2[0], e1 = wr2[1], e2  = wr2[2],  e3  = wr2[3],  e4  = wr2[4],  e5  = wr2[5];
        float4 e6 = wr2[6], e7 = wr2[7], e8  = wr2[8],  e9  = wr2[9],  e10 = wr2[10], e11 = wr2[11];
        h2 W24 = mkh2(e0.x,  e0.y),  W25 = mkh2(e0.z,  e0.w);
        h2 W26 = mkh2(e1.x,  e1.y),  W27 = mkh2(e1.z,  e1.w);
        h2 W28 = mkh2(e2.x,  e2.y),  W29 = mkh2(e2.z,  e2.w);
        h2 W30 = mkh2(e3.x,  e3.y),  W31 = mkh2(e3.z,  e3.w);
        h2 W32 = mkh2(e4.x,  e4.y),  W33 = mkh2(e4.z,  e4.w);
        h2 W34 = mkh2(e5.x,  e5.y),  W35 = mkh2(e5.z,  e5.w);
        h2 W36 = mkh2(e6.x,  e6.y),  W37 = mkh2(e6.z,  e6.w);
        h2 W38 = mkh2(e7.x,  e7.y),  W39 = mkh2(e7.z,  e7.w);
        h2 W40 = mkh2(e8.x,  e8.y),  W41 = mkh2(e8.z,  e8.w);
        h2 W42 = mkh2(e9.x,  e9.y),  W43 = mkh2(e9.z,  e9.w);
        h2 W44 = mkh2(e10.x, e10.y), W45 = mkh2(e10.z, e10.w);
        h2 W46 = mkh2(e11.x, e11.y), W47 = mkh2(e11.z, e11.w);
        asm("" : "+v"(W0),  "+v"(W1),  "+v"(W2),  "+v"(W3),  "+v"(W4),  "+v"(W5));
        asm("" : "+v"(W6),  "+v"(W7),  "+v"(W8),  "+v"(W9),  "+v"(W10), "+v"(W11));
        asm("" : "+v"(W12), "+v"(W13), "+v"(W14), "+v"(W15), "+v"(W16), "+v"(W17));
        asm("" : "+v"(W18), "+v"(W19), "+v"(W20), "+v"(W21), "+v"(W22), "+v"(W23));
        asm("" : "+v"(W24), "+v"(W25), "+v"(W26), "+v"(W27), "+v"(W28), "+v"(W29));
        asm("" : "+v"(W30), "+v"(W31), "+v"(W32), "+v"(W33), "+v"(W34), "+v"(W35));
        asm("" : "+v"(W36), "+v"(W37), "+v"(W38), "+v"(W39), "+v"(W40), "+v"(W41));
        asm("" : "+v"(W42), "+v"(W43), "+v"(W44), "+v"(W45), "+v"(W46), "+v"(W47));

        const float wihr = w_ih[j];
        const float bias = b_ih[j] + b_hh[j];
        // gate g==2 is tanh = 2*sig(2x)-1; others sigmoid.
        const bool  isg = (g == 2);
        const float nk  = isg ? -2.885390082f : -1.442695041f;  // -s1*log2(e)
        const float m1  = isg ? 2.f : 1.f;
        const float d1  = isg ? -1.f : 0.f;

        float c  = 0.f;
        float xs = xrow[0];

        #pragma unroll 1
        for (int t = 0; t < T; ++t) {
            int tn = t + 1; tn = (tn < T) ? tn : (T - 1);
            float xs_n = xrow[tn];

            const uint4* hp = reinterpret_cast<const uint4*>(hbuf[(t & 1) ^ 1]);
            float acc0 = 0.f, acc1 = 0.f, acc2 = 0.f, acc3 = 0.f;
            uint4 qA = hp[0], qB = hp[1], qC = hp[2];
            DOT4(qA, 0, 1, 2, 3);     qA = hp[3];
            DOT4(qB, 4, 5, 6, 7);     qB = hp[4];
            DOT4(qC, 8, 9, 10, 11);   qC = hp[5];
            DOT4(qA, 12, 13, 14, 15); qA = hp[6];
            DOT4(qB, 16, 17, 18, 19); qB = hp[7];
            DOT4(qC, 20, 21, 22, 23); qC = hp[8];
            DOT4(qA, 24, 25, 26, 27); qA = hp[9];
            DOT4(qB, 28, 29, 30, 31); qB = hp[10];
            DOT4(qC, 32, 33, 34, 35); qC = hp[11];
            DOT4(qA, 36, 37, 38, 39);
            DOT4(qB, 40, 41, 42, 43);
            DOT4(qC, 44, 45, 46, 47);

            float v    = (acc0 + acc1) + (acc2 + acc3);
            float pre  = v + fmaf(xs, wihr, bias);
            float actv = fmaf(m1, __builtin_amdgcn_rcpf(1.f + __builtin_exp2f(pre * nk)), d1);

            // gather the other 3 gates of this unit via quad-perm DPP (VALU)
            float x1 = dpp_q<0xB1>(actv);   // lane^1
            float x2 = dpp_q<0x4E>(actv);   // lane^2
            float x3 = dpp_q<0x1B>(actv);   // lane^3

            if ((lane & 3) == 0) {   // i-lane owns unit u: actv=i, x1=f, x2=g, x3=o
                c = fmaf(x1, c, actv * x2);
                float th = fmaf(2.f, __builtin_amdgcn_rcpf(1.f + __builtin_exp2f(c * -2.885390082f)), -1.f);
                float h  = x3 * th;
                hbuf[t & 1][u] = (_Float16)h;          // matvec path (f16)
                hist[(t >> 6) & 1][t & 63][u] = h;     // head path (f32)
            }
            BARRIER();
            xs = xs_n;
        }
    } else {
        // ---- head wave: one burst of 64 outputs per 64-step window ----
        const float bd = b_dense[0];
        #pragma unroll 1
        for (int t = 0; t < T; ++t) {
            if (t && (t & 63) == 0) {
                const int buf = ((t >> 6) - 1) & 1;    // completed window's buffer
                float a = head_dot(&hist[buf][lane][0], w_dense);
                orow[t - 64 + lane] = a + bd;
            }
            BARRIER();
        }
        // tail: rows [T0, T)
        const int T0 = ((T - 1) >> 6) << 6;
        if (lane < T - T0) {
            const int buf = (T0 >> 6) & 1;
            float a = head_dot(&hist[buf][lane][0], w_dense);
            orow[T0 + lane] = a + bd;
        }
    }
}

extern "C" void kernel_launch(void* const* d_in, const int* in_sizes, int n_in,
                              void* d_out, int out_size, void* d_ws, size_t ws_size,
                              hipStream_t stream) {
    const float* x   = (const float*)d_in[0];
    const float* wih = (const float*)d_in[1];
    const float* whh = (const float*)d_in[2];
    const float* bih = (const float*)d_in[3];
    const float* bhh = (const float*)d_in[4];
    const float* wd  = (const float*)d_in[5];
    const float* bd  = (const float*)d_in[6];
    float* out = (float*)d_out;

    const int B = 32;
    const int T = in_sizes[0] / B;   // x is [B,T,1]

    lstm_fused<<<dim3(B), dim3(448), 0, stream>>>(x, wih, whh, bih, bhh, wd, bd, out, T);
}